// Round 13
// baseline (1127.771 us; speedup 1.0000x reference)
//
#include <hip/hip_runtime.h>

#define NNODES 100000
#define NEDGES 200000
#define NB     2048
#define DIM    256
#define NLAYERS 5
#define NSB    98   // ceil(100000/1024) scan blocks

typedef __bf16 bf16x8 __attribute__((ext_vector_type(8)));
typedef float  f32x4  __attribute__((ext_vector_type(4)));

__device__ __forceinline__ float bf2f(unsigned short u) {
    union { unsigned u; float f; } v; v.u = ((unsigned)u) << 16; return v.f;
}
__device__ __forceinline__ unsigned short f2bf(float f) {
    union { float f; unsigned u; } v; v.f = f;
    unsigned r = v.u + 0x7fff + ((v.u >> 16) & 1);   // RNE (finite values only)
    return (unsigned short)(r >> 16);
}
__device__ __forceinline__ float4 loadZ4(const unsigned short* z, size_t row, int ch) {
    ushort4 u = *(const ushort4*)&z[row * DIM + ch];
    float4 r; r.x = bf2f(u.x); r.y = bf2f(u.y); r.z = bf2f(u.z); r.w = bf2f(u.w); return r;
}

__global__ void zero_i32(int* __restrict__ p, int n) {
    int i = blockIdx.x * 256 + threadIdx.x;
    if (i < n) p[i] = 0;
}
__global__ void zero_f32(float* __restrict__ p, int n) {
    int i = blockIdx.x * 256 + threadIdx.x;
    if (i < n) p[i] = 0.f;
}

// ---- transpose+convert weights: W (L x K x Nw) fp32 -> Wt (L x Nw x K) bf16 ----
__global__ void transpose_w(const float* __restrict__ W,
                            unsigned short* __restrict__ Wt, int K, int Nw) {
    int l = blockIdx.y;
    int t = blockIdx.x * 256 + threadIdx.x;
    int total = K * Nw;
    if (t >= total) return;
    int k = t / Nw, n = t % Nw;
    Wt[(size_t)l * total + (size_t)n * K + k] = f2bf(W[(size_t)l * total + t]);
}

// ---- edge-embedding table ----
__global__ void build_etab(const float* __restrict__ ee1, const float* __restrict__ ee2,
                           float* __restrict__ etab) {
    int l = blockIdx.y, c = blockIdx.x, d = threadIdx.x;   // c in [0,15)
    etab[((size_t)l * 15 + c) * DIM + d] =
        ee1[((size_t)l * 5 + c / 3) * DIM + d] + ee2[((size_t)l * 3 + c % 3) * DIM + d];
}

// ---- CSR build ----
__global__ void csr_hist(const int* __restrict__ ei, int* __restrict__ deg) {
    int j = blockIdx.x * 256 + threadIdx.x;
    if (j < NEDGES) atomicAdd(&deg[ei[NEDGES + j]], 1);
}
__global__ __launch_bounds__(1024) void scan_blk(const int* __restrict__ deg,
                                                 int* __restrict__ rowptr,
                                                 int* __restrict__ bsum) {
    __shared__ int s[1024];
    int b = blockIdx.x, t = threadIdx.x, i = b * 1024 + t;
    s[t] = (i < NNODES) ? deg[i] : 0;
    __syncthreads();
    #pragma unroll
    for (int off = 1; off < 1024; off <<= 1) {
        int u = (t >= off) ? s[t - off] : 0;
        __syncthreads();
        s[t] += u;
        __syncthreads();
    }
    if (i < NNODES) rowptr[i + 1] = s[t];
    if (t == 1023) bsum[b] = s[1023];
}
__global__ void scan_partials(int* __restrict__ bsum) {
    if (threadIdx.x == 0) {
        int acc = 0;
        for (int k = 0; k < NSB; ++k) { acc += bsum[k]; bsum[k] = acc; }
    }
}
__global__ void scan_add(int* __restrict__ rowptr, const int* __restrict__ bsum) {
    int b = blockIdx.x, t = threadIdx.x, i = b * 1024 + t;
    if (b > 0 && i < NNODES) rowptr[i + 1] += bsum[b - 1];
    if (b == 0 && t == 0) rowptr[0] = 0;
}
__global__ void csr_fill(const int* __restrict__ ei, const int* __restrict__ ea,
                         const int* __restrict__ rowptr, int* __restrict__ deg,
                         int* __restrict__ esrc, int* __restrict__ eattr) {
    int j = blockIdx.x * 256 + threadIdx.x;
    if (j >= NEDGES) return;
    int d = ei[NEDGES + j];
    int pos = atomicSub(&deg[d], 1) - 1;
    int slot = rowptr[d] + pos;
    esrc[slot] = ei[j];
    eattr[slot] = ea[2 * j] * 3 + ea[2 * j + 1];
}

// ---- segment starts ----
__global__ void seg_starts(const int* __restrict__ batch, int* __restrict__ start) {
    int g = blockIdx.x * 256 + threadIdx.x;
    if (g > NB) return;
    int lo = 0, hi = NNODES;
    while (lo < hi) { int mid = (lo + hi) >> 1; if (batch[mid] < g) lo = mid + 1; else hi = mid; }
    start[g] = lo;
}

// ---- fused layer: gather -> As -> quarter-split 2-GEMM (Ts double-buffered) -> zdst ----
// (512,4): 128-reg budget so the 4-deep b-fragment hoists can actually stay in flight.
// Double-buffered Ts needs only ONE barrier per quarter (barrier(q) separates
// stage2(q-1) reads of Ts[(q+1)&1] from stage1(q+1) writes of the same buffer).
template <int MODE>
__global__ __launch_bounds__(512, 4) void layer_k(const unsigned short* __restrict__ zsrc,
                                                  unsigned short* __restrict__ zdst,
                                                  const int* __restrict__ x,
                                                  const float* __restrict__ xe1,
                                                  const float* __restrict__ xe2,
                                                  const float* __restrict__ statsP,
                                                  float* __restrict__ statsZ,
                                                  const float* __restrict__ g_,
                                                  const float* __restrict__ b_,
                                                  const float* __restrict__ etab_l,
                                                  const int* __restrict__ rowptr,
                                                  const int* __restrict__ esrc,
                                                  const int* __restrict__ eattr,
                                                  const unsigned short* __restrict__ Wt1,
                                                  const float* __restrict__ b1,
                                                  const unsigned short* __restrict__ Wt2,
                                                  const float* __restrict__ b2,
                                                  float* __restrict__ stats) {
    __shared__ unsigned short As[64 * 264];      // 33792 B
    __shared__ unsigned short Ts[2][64 * 136];   // 2 x 17408 B (double-buffered t-quarter)

    const int rowBase = blockIdx.x * 64;
    const int tid = threadIdx.x;
    const int lane = tid & 63, w = tid >> 6;
    const int lrow = lane & 15, lq = lane >> 4;

    if (blockIdx.x == 0) statsZ[tid] = 0.f;

    // ---- stage A: fused gather into As ----
    {
        const int ch = lane * 4;
        float4 a4, c4;
        if (MODE == 1) {
            float4 s4 = *(const float4*)&statsP[ch];
            float4 q4 = *(const float4*)&statsP[256 + ch];
            float4 g4 = *(const float4*)&g_[ch];
            float4 b4 = *(const float4*)&b_[ch];
            const float invN = 1.0f / (float)NNODES;
            float mux = s4.x * invN, muy = s4.y * invN, muz = s4.z * invN, muw = s4.w * invN;
            a4.x = g4.x * rsqrtf(q4.x * invN - mux * mux + 1e-5f);
            a4.y = g4.y * rsqrtf(q4.y * invN - muy * muy + 1e-5f);
            a4.z = g4.z * rsqrtf(q4.z * invN - muz * muz + 1e-5f);
            a4.w = g4.w * rsqrtf(q4.w * invN - muw * muw + 1e-5f);
            c4.x = b4.x - mux * a4.x; c4.y = b4.y - muy * a4.y;
            c4.z = b4.z - muz * a4.z; c4.w = b4.w - muw * a4.w;
        }
        auto hrow = [&](int row) -> float4 {
            if (MODE == 0) {
                int i0 = x[2 * row], i1 = x[2 * row + 1];
                float4 u = *(const float4*)&xe1[(size_t)i0 * DIM + ch];
                float4 v = *(const float4*)&xe2[(size_t)i1 * DIM + ch];
                return make_float4(u.x + v.x, u.y + v.y, u.z + v.z, u.w + v.w);
            } else {
                float4 h = loadZ4(zsrc, (size_t)row, ch);
                h.x = fmaxf(h.x * a4.x + c4.x, 0.f); h.y = fmaxf(h.y * a4.y + c4.y, 0.f);
                h.z = fmaxf(h.z * a4.z + c4.z, 0.f); h.w = fmaxf(h.w * a4.w + c4.w, 0.f);
                return h;
            }
        };
        float4 se = *(const float4*)&etab_l[12 * DIM + ch];   // self edge (bt=4,bd=0)
        #pragma unroll
        for (int r8 = 0; r8 < 8; ++r8) {
            int row = rowBase + w * 8 + r8;
            float4 acc = make_float4(0.f, 0.f, 0.f, 0.f);
            if (row < NNODES) {
                float4 hv = hrow(row);
                acc = make_float4(hv.x + se.x, hv.y + se.y, hv.z + se.z, hv.w + se.w);
                int r0 = rowptr[row], r1 = rowptr[row + 1];
                int e = r0;
                for (; e + 2 <= r1; e += 2) {
                    int s0 = esrc[e], c0 = eattr[e];
                    int s1 = esrc[e + 1], c1 = eattr[e + 1];
                    float4 h0 = hrow(s0);
                    float4 h1 = hrow(s1);
                    float4 e0 = *(const float4*)&etab_l[c0 * DIM + ch];
                    float4 e1 = *(const float4*)&etab_l[c1 * DIM + ch];
                    acc.x += h0.x + e0.x + h1.x + e1.x; acc.y += h0.y + e0.y + h1.y + e1.y;
                    acc.z += h0.z + e0.z + h1.z + e1.z; acc.w += h0.w + e0.w + h1.w + e1.w;
                }
                if (e < r1) {
                    int s0 = esrc[e], c0 = eattr[e];
                    float4 h0 = hrow(s0);
                    float4 e0 = *(const float4*)&etab_l[c0 * DIM + ch];
                    acc.x += h0.x + e0.x; acc.y += h0.y + e0.y;
                    acc.z += h0.z + e0.z; acc.w += h0.w + e0.w;
                }
            }
            ushort4 o; o.x = f2bf(acc.x); o.y = f2bf(acc.y); o.z = f2bf(acc.z); o.w = f2bf(acc.w);
            *(ushort4*)&As[(w * 8 + r8) * 264 + ch] = o;
        }
    }
    f32x4 acc2[4][2]{};
    __syncthreads();

    // ---- quarter-split GEMM: double-buffered Ts, one barrier/quarter, hoisted b-loads ----
    #pragma unroll
    for (int q = 0; q < 4; ++q) {
        unsigned short* Tb = Ts[q & 1];
        f32x4 acc1[4]{};
        const unsigned short* w1p = &Wt1[(size_t)(q * 128 + w * 16 + lrow) * DIM];
        #pragma unroll
        for (int g2 = 0; g2 < 2; ++g2) {        // two groups of 4 kk each
            bf16x8 bq[4];
            #pragma unroll
            for (int j = 0; j < 4; ++j)
                bq[j] = *(const bf16x8*)&w1p[(g2 * 4 + j) * 32 + lq * 8];
            #pragma unroll
            for (int j = 0; j < 4; ++j) {
                const int kc = (g2 * 4 + j) * 32 + lq * 8;
                bf16x8 a[4];
                #pragma unroll
                for (int mi = 0; mi < 4; ++mi)
                    a[mi] = *(const bf16x8*)&As[(mi * 16 + lrow) * 264 + kc];
                #pragma unroll
                for (int mi = 0; mi < 4; ++mi)
                    acc1[mi] = __builtin_amdgcn_mfma_f32_16x16x32_bf16(a[mi], bq[j], acc1[mi], 0, 0, 0);
            }
        }
        {
            int col = w * 16 + lrow;
            float bv = b1[q * 128 + col];
            #pragma unroll
            for (int mi = 0; mi < 4; ++mi)
                #pragma unroll
                for (int r = 0; r < 4; ++r)
                    Tb[(mi * 16 + lq * 4 + r) * 136 + col] = f2bf(fmaxf(acc1[mi][r] + bv, 0.f));
        }
        __syncthreads();   // the only barrier in the quarter
        // stage 2: acc2 += Tb @ W2[k-slice]; b hoisted in two groups of 4
        #pragma unroll
        for (int g2 = 0; g2 < 2; ++g2) {        // kk pairs (g2*2, g2*2+1) x ni(2)
            bf16x8 bq[4];
            #pragma unroll
            for (int j = 0; j < 4; ++j) {
                int kk = g2 * 2 + (j >> 1), ni = j & 1;
                bq[j] = *(const bf16x8*)&Wt2[(size_t)(w * 32 + ni * 16 + lrow) * (2 * DIM) + q * 128 + kk * 32 + lq * 8];
            }
            #pragma unroll
            for (int kj = 0; kj < 2; ++kj) {
                const int kk = g2 * 2 + kj;
                const int kc = kk * 32 + lq * 8;
                bf16x8 a[4];
                #pragma unroll
                for (int mi = 0; mi < 4; ++mi)
                    a[mi] = *(const bf16x8*)&Tb[(mi * 16 + lrow) * 136 + kc];
                #pragma unroll
                for (int mi = 0; mi < 4; ++mi)
                    #pragma unroll
                    for (int ni = 0; ni < 2; ++ni)
                        acc2[mi][ni] = __builtin_amdgcn_mfma_f32_16x16x32_bf16(a[mi], bq[kj * 2 + ni], acc2[mi][ni], 0, 0, 0);
            }
        }
    }

    // ---- epilogue: zdst store + stats atomics ----
    #pragma unroll
    for (int ni = 0; ni < 2; ++ni) {
        int col = w * 32 + ni * 16 + lrow;
        float bv = b2[col];
        float s = 0.f, q = 0.f;
        #pragma unroll
        for (int mi = 0; mi < 4; ++mi)
            #pragma unroll
            for (int r = 0; r < 4; ++r) {
                int row = rowBase + mi * 16 + lq * 4 + r;
                if (row < NNODES) {
                    float v = acc2[mi][ni][r] + bv;
                    zdst[(size_t)row * DIM + col] = f2bf(v);
                    s += v; q += v * v;
                }
            }
        s += __shfl_xor(s, 16); s += __shfl_xor(s, 32);
        q += __shfl_xor(q, 16); q += __shfl_xor(q, 32);
        if (lq == 0) {
            atomicAdd(&stats[col], s);
            atomicAdd(&stats[DIM + col], q);
        }
    }
}

// ---- pooled[g] = mean(relu(z*a+c)) over sorted segment; BN inline from stats ----
__global__ __launch_bounds__(256) void pool_seg(const unsigned short* __restrict__ z,
                                                const float* __restrict__ statsP,
                                                const float* __restrict__ g_,
                                                const float* __restrict__ b_,
                                                const int* __restrict__ start,
                                                float* __restrict__ pooled) {
    int g = blockIdx.x, ch = threadIdx.x;
    float mu = statsP[ch] / (float)NNODES;
    float var = statsP[256 + ch] / (float)NNODES - mu * mu;
    float a = g_[ch] * rsqrtf(var + 1e-5f);
    float c = b_[ch] - mu * a;
    int r0 = start[g], r1 = start[g + 1];
    float s = 0.f;
    for (int i = r0; i < r1; ++i)
        s += fmaxf(bf2f(z[(size_t)i * DIM + ch]) * a + c, 0.f);
    pooled[(size_t)g * DIM + ch] = s / fmaxf((float)(r1 - r0), 1.f);
}

// ---- head MLP ----
__global__ __launch_bounds__(128) void head_mlp(const float* __restrict__ pooled,
                                                const float* __restrict__ Wo1,
                                                const float* __restrict__ bo1,
                                                const float* __restrict__ Wo2,
                                                const float* __restrict__ bo2,
                                                float* __restrict__ out) {
    __shared__ float p[DIM];
    __shared__ float r0[128], r1[128];
    int g = blockIdx.x, j = threadIdx.x;
    for (int k = j; k < DIM; k += 128) p[k] = pooled[(size_t)g * DIM + k];
    __syncthreads();
    float acc = bo1[j];
    for (int k = 0; k < DIM; ++k) acc += p[k] * Wo1[k * 128 + j];
    float sp = (acc > 20.f) ? acc : log1pf(expf(acc));
    r0[j] = sp * Wo2[j * 2 + 0];
    r1[j] = sp * Wo2[j * 2 + 1];
    __syncthreads();
    for (int s = 64; s > 0; s >>= 1) {
        if (j < s) { r0[j] += r0[j + s]; r1[j] += r1[j + s]; }
        __syncthreads();
    }
    if (j == 0) {
        out[g * 2 + 0] = r0[0] + bo2[0];
        out[g * 2 + 1] = r1[0] + bo2[1];
    }
}

extern "C" void kernel_launch(void* const* d_in, const int* in_sizes, int n_in,
                              void* d_out, int out_size, void* d_ws, size_t ws_size,
                              hipStream_t stream) {
    (void)in_sizes; (void)n_in; (void)out_size;
    const int* x     = (const int*)d_in[0];
    const int* ei    = (const int*)d_in[1];
    const int* ea    = (const int*)d_in[2];
    const int* batch = (const int*)d_in[3];
    const float* xe1 = (const float*)d_in[4];
    const float* xe2 = (const float*)d_in[5];
    const float* ee1 = (const float*)d_in[6];
    const float* ee2 = (const float*)d_in[7];
    const float* W1  = (const float*)d_in[8];
    const float* b1  = (const float*)d_in[9];
    const float* W2  = (const float*)d_in[10];
    const float* b2  = (const float*)d_in[11];
    const float* bng = (const float*)d_in[12];
    const float* bnb = (const float*)d_in[13];
    const float* Wo1 = (const float*)d_in[14];
    const float* bo1 = (const float*)d_in[15];
    const float* Wo2 = (const float*)d_in[16];
    const float* bo2 = (const float*)d_in[17];
    float* out = (float*)d_out;

    if (ws_size < 112000000ull) return;   // need ~109 MB

    char* ws = (char*)d_ws;
    size_t off = 0;
    auto alloc = [&](size_t bytes) { void* p = ws + off; off += (bytes + 255) & ~255ull; return p; };
    unsigned short* zA  = (unsigned short*)alloc((size_t)NNODES * DIM * 2);
    unsigned short* zB  = (unsigned short*)alloc((size_t)NNODES * DIM * 2);
    unsigned short* Wt1 = (unsigned short*)alloc((size_t)NLAYERS * DIM * 2 * DIM * 2);
    unsigned short* Wt2 = (unsigned short*)alloc((size_t)NLAYERS * DIM * 2 * DIM * 2);
    float* etab         = (float*)alloc((size_t)NLAYERS * 15 * DIM * 4);
    float* stats        = (float*)alloc(3 * 512 * 4);          // 3-rotation [3][512]
    float* pooled       = (float*)alloc((size_t)NB * DIM * 4);
    int* gstart         = (int*)alloc((size_t)(NB + 1) * 4);
    int* rowptr         = (int*)alloc((size_t)(NNODES + 1) * 4);
    int* deg            = (int*)alloc((size_t)NNODES * 4);
    int* esrc           = (int*)alloc((size_t)NEDGES * 4);
    int* eattr          = (int*)alloc((size_t)NEDGES * 4);
    int* bsum           = (int*)alloc((size_t)NSB * 4);

    const int WTOT = DIM * 2 * DIM;  // 131072
    unsigned short* zb[2] = { zA, zB };

    transpose_w<<<dim3((WTOT + 255) / 256, NLAYERS), 256, 0, stream>>>(W1, Wt1, DIM, 2 * DIM);
    transpose_w<<<dim3((WTOT + 255) / 256, NLAYERS), 256, 0, stream>>>(W2, Wt2, 2 * DIM, DIM);
    build_etab<<<dim3(15, NLAYERS), DIM, 0, stream>>>(ee1, ee2, etab);
    zero_f32<<<2, 256, 0, stream>>>(stats, 512);   // layer 0's stats buffer

    zero_i32<<<(NNODES + 255) / 256, 256, 0, stream>>>(deg, NNODES);
    csr_hist<<<(NEDGES + 255) / 256, 256, 0, stream>>>(ei, deg);
    scan_blk<<<NSB, 1024, 0, stream>>>(deg, rowptr, bsum);
    scan_partials<<<1, 64, 0, stream>>>(bsum);
    scan_add<<<NSB, 1024, 0, stream>>>(rowptr, bsum);
    csr_fill<<<(NEDGES + 255) / 256, 256, 0, stream>>>(ei, ea, rowptr, deg, esrc, eattr);
    seg_starts<<<(NB + 1 + 255) / 256, 256, 0, stream>>>(batch, gstart);

    const int NBLK = (NNODES + 63) / 64;
    for (int l = 0; l < NLAYERS; ++l) {
        float* statsC = stats + (size_t)(l % 3) * 512;
        float* statsP = stats + (size_t)((l + 2) % 3) * 512;
        float* statsZ = stats + (size_t)((l + 1) % 3) * 512;
        if (l == 0)
            layer_k<0><<<NBLK, 512, 0, stream>>>(zb[0], zb[1], x, xe1, xe2, statsP, statsZ,
                                                 bng, bnb, etab, rowptr, esrc, eattr,
                                                 Wt1, b1, Wt2, b2, statsC);
        else
            layer_k<1><<<NBLK, 512, 0, stream>>>(zb[l & 1], zb[(l + 1) & 1], x, xe1, xe2, statsP, statsZ,
                                                 bng + (size_t)(l - 1) * DIM, bnb + (size_t)(l - 1) * DIM,
                                                 etab + (size_t)l * 15 * DIM, rowptr, esrc, eattr,
                                                 Wt1 + (size_t)l * WTOT, b1 + (size_t)l * 2 * DIM,
                                                 Wt2 + (size_t)l * WTOT, b2 + (size_t)l * DIM, statsC);
    }

    pool_seg<<<NB, DIM, 0, stream>>>(zb[NLAYERS & 1], stats + (size_t)((NLAYERS - 1) % 3) * 512,
                                     bng + (size_t)(NLAYERS - 1) * DIM, bnb + (size_t)(NLAYERS - 1) * DIM,
                                     gstart, pooled);
    head_mlp<<<NB, 128, 0, stream>>>(pooled, Wo1, bo1, Wo2, bo2, out);
}

// Round 16
// 1055.730 us; speedup vs baseline: 1.0682x; 1.0682x over previous
//
#include <hip/hip_runtime.h>

#define NNODES 100000
#define NEDGES 200000
#define NB     2048
#define DIM    256
#define NLAYERS 5
#define NSB    98   // ceil(100000/1024) scan blocks

typedef __bf16 bf16x8 __attribute__((ext_vector_type(8)));
typedef float  f32x4  __attribute__((ext_vector_type(4)));

__device__ __forceinline__ float bf2f(unsigned short u) {
    union { unsigned u; float f; } v; v.u = ((unsigned)u) << 16; return v.f;
}
__device__ __forceinline__ unsigned short f2bf(float f) {
    union { float f; unsigned u; } v; v.f = f;
    unsigned r = v.u + 0x7fff + ((v.u >> 16) & 1);   // RNE (finite values only)
    return (unsigned short)(r >> 16);
}
__device__ __forceinline__ float4 loadZ4(const unsigned short* z, size_t row, int ch) {
    ushort4 u = *(const ushort4*)&z[row * DIM + ch];
    float4 r; r.x = bf2f(u.x); r.y = bf2f(u.y); r.z = bf2f(u.z); r.w = bf2f(u.w); return r;
}

__global__ void zero_i32(int* __restrict__ p, int n) {
    int i = blockIdx.x * 256 + threadIdx.x;
    if (i < n) p[i] = 0;
}
__global__ void zero_f32(float* __restrict__ p, int n) {
    int i = blockIdx.x * 256 + threadIdx.x;
    if (i < n) p[i] = 0.f;
}

// ---- transpose+convert weights: W (L x K x Nw) fp32 -> Wt (L x Nw x K) bf16 ----
__global__ void transpose_w(const float* __restrict__ W,
                            unsigned short* __restrict__ Wt, int K, int Nw) {
    int l = blockIdx.y;
    int t = blockIdx.x * 256 + threadIdx.x;
    int total = K * Nw;
    if (t >= total) return;
    int k = t / Nw, n = t % Nw;
    Wt[(size_t)l * total + (size_t)n * K + k] = f2bf(W[(size_t)l * total + t]);
}

// ---- edge-embedding table ----
__global__ void build_etab(const float* __restrict__ ee1, const float* __restrict__ ee2,
                           float* __restrict__ etab) {
    int l = blockIdx.y, c = blockIdx.x, d = threadIdx.x;   // c in [0,15)
    etab[((size_t)l * 15 + c) * DIM + d] =
        ee1[((size_t)l * 5 + c / 3) * DIM + d] + ee2[((size_t)l * 3 + c % 3) * DIM + d];
}

// ---- CSR build ----
__global__ void csr_hist(const int* __restrict__ ei, int* __restrict__ deg) {
    int j = blockIdx.x * 256 + threadIdx.x;
    if (j < NEDGES) atomicAdd(&deg[ei[NEDGES + j]], 1);
}
__global__ __launch_bounds__(1024) void scan_blk(const int* __restrict__ deg,
                                                 int* __restrict__ rowptr,
                                                 int* __restrict__ bsum) {
    __shared__ int s[1024];
    int b = blockIdx.x, t = threadIdx.x, i = b * 1024 + t;
    s[t] = (i < NNODES) ? deg[i] : 0;
    __syncthreads();
    #pragma unroll
    for (int off = 1; off < 1024; off <<= 1) {
        int u = (t >= off) ? s[t - off] : 0;
        __syncthreads();
        s[t] += u;
        __syncthreads();
    }
    if (i < NNODES) rowptr[i + 1] = s[t];
    if (t == 1023) bsum[b] = s[1023];
}
__global__ void scan_partials(int* __restrict__ bsum) {
    if (threadIdx.x == 0) {
        int acc = 0;
        for (int k = 0; k < NSB; ++k) { acc += bsum[k]; bsum[k] = acc; }
    }
}
__global__ void scan_add(int* __restrict__ rowptr, const int* __restrict__ bsum) {
    int b = blockIdx.x, t = threadIdx.x, i = b * 1024 + t;
    if (b > 0 && i < NNODES) rowptr[i + 1] += bsum[b - 1];
    if (b == 0 && t == 0) rowptr[0] = 0;
}
__global__ void csr_fill(const int* __restrict__ ei, const int* __restrict__ ea,
                         const int* __restrict__ rowptr, int* __restrict__ deg,
                         int* __restrict__ esrc, int* __restrict__ eattr) {
    int j = blockIdx.x * 256 + threadIdx.x;
    if (j >= NEDGES) return;
    int d = ei[NEDGES + j];
    int pos = atomicSub(&deg[d], 1) - 1;
    int slot = rowptr[d] + pos;
    esrc[slot] = ei[j];
    eattr[slot] = ea[2 * j] * 3 + ea[2 * j + 1];
}

// ---- segment starts ----
__global__ void seg_starts(const int* __restrict__ batch, int* __restrict__ start) {
    int g = blockIdx.x * 256 + threadIdx.x;
    if (g > NB) return;
    int lo = 0, hi = NNODES;
    while (lo < hi) { int mid = (lo + hi) >> 1; if (batch[mid] < g) lo = mid + 1; else hi = mid; }
    start[g] = lo;
}

// ---- fused layer: gather (CSR + BN + edge-emb) -> LDS -> 2-GEMM MLP -> zdst + stats ----
// MODE 0: h = xe1[x0]+xe2[x1] (layer 0). MODE 1: h = relu(zsrc*a+c), BN inline from statsP.
template <int MODE>
__global__ __launch_bounds__(512, 6) void layer_k(const unsigned short* __restrict__ zsrc,
                                                  unsigned short* __restrict__ zdst,
                                                  const int* __restrict__ x,
                                                  const float* __restrict__ xe1,
                                                  const float* __restrict__ xe2,
                                                  const float* __restrict__ statsP,
                                                  float* __restrict__ statsZ,
                                                  const float* __restrict__ g_,
                                                  const float* __restrict__ b_,
                                                  const float* __restrict__ etab_l,
                                                  const int* __restrict__ rowptr,
                                                  const int* __restrict__ esrc,
                                                  const int* __restrict__ eattr,
                                                  const unsigned short* __restrict__ Wt1,
                                                  const float* __restrict__ b1,
                                                  const unsigned short* __restrict__ Wt2,
                                                  const float* __restrict__ b2,
                                                  float* __restrict__ stats) {
    __shared__ unsigned short As[64 * 264];   // 33792 B
    __shared__ unsigned short Ts[64 * 136];   // 17408 B (one t-quarter)

    const int rowBase = blockIdx.x * 64;
    const int tid = threadIdx.x;
    const int lane = tid & 63, w = tid >> 6;
    const int lrow = lane & 15, lq = lane >> 4;

    if (blockIdx.x == 0) statsZ[tid] = 0.f;

    // ---- stage A: fused gather into As ----
    {
        const int ch = lane * 4;
        float4 a4, c4;
        if (MODE == 1) {
            float4 s4 = *(const float4*)&statsP[ch];
            float4 q4 = *(const float4*)&statsP[256 + ch];
            float4 g4 = *(const float4*)&g_[ch];
            float4 b4 = *(const float4*)&b_[ch];
            const float invN = 1.0f / (float)NNODES;
            float mux = s4.x * invN, muy = s4.y * invN, muz = s4.z * invN, muw = s4.w * invN;
            a4.x = g4.x * rsqrtf(q4.x * invN - mux * mux + 1e-5f);
            a4.y = g4.y * rsqrtf(q4.y * invN - muy * muy + 1e-5f);
            a4.z = g4.z * rsqrtf(q4.z * invN - muz * muz + 1e-5f);
            a4.w = g4.w * rsqrtf(q4.w * invN - muw * muw + 1e-5f);
            c4.x = b4.x - mux * a4.x; c4.y = b4.y - muy * a4.y;
            c4.z = b4.z - muz * a4.z; c4.w = b4.w - muw * a4.w;
        }
        auto hrow = [&](int row) -> float4 {
            if (MODE == 0) {
                int i0 = x[2 * row], i1 = x[2 * row + 1];
                float4 u = *(const float4*)&xe1[(size_t)i0 * DIM + ch];
                float4 v = *(const float4*)&xe2[(size_t)i1 * DIM + ch];
                return make_float4(u.x + v.x, u.y + v.y, u.z + v.z, u.w + v.w);
            } else {
                float4 h = loadZ4(zsrc, (size_t)row, ch);
                h.x = fmaxf(h.x * a4.x + c4.x, 0.f); h.y = fmaxf(h.y * a4.y + c4.y, 0.f);
                h.z = fmaxf(h.z * a4.z + c4.z, 0.f); h.w = fmaxf(h.w * a4.w + c4.w, 0.f);
                return h;
            }
        };
        float4 se = *(const float4*)&etab_l[12 * DIM + ch];   // self edge (bt=4,bd=0)
        #pragma unroll
        for (int r8 = 0; r8 < 8; ++r8) {
            int row = rowBase + w * 8 + r8;
            float4 acc = make_float4(0.f, 0.f, 0.f, 0.f);
            if (row < NNODES) {
                float4 hv = hrow(row);
                acc = make_float4(hv.x + se.x, hv.y + se.y, hv.z + se.z, hv.w + se.w);
                int r0 = rowptr[row], r1 = rowptr[row + 1];
                int e = r0;
                for (; e + 2 <= r1; e += 2) {
                    int s0 = esrc[e], c0 = eattr[e];
                    int s1 = esrc[e + 1], c1 = eattr[e + 1];
                    float4 h0 = hrow(s0);
                    float4 h1 = hrow(s1);
                    float4 e0 = *(const float4*)&etab_l[c0 * DIM + ch];
                    float4 e1 = *(const float4*)&etab_l[c1 * DIM + ch];
                    acc.x += h0.x + e0.x + h1.x + e1.x; acc.y += h0.y + e0.y + h1.y + e1.y;
                    acc.z += h0.z + e0.z + h1.z + e1.z; acc.w += h0.w + e0.w + h1.w + e1.w;
                }
                if (e < r1) {
                    int s0 = esrc[e], c0 = eattr[e];
                    float4 h0 = hrow(s0);
                    float4 e0 = *(const float4*)&etab_l[c0 * DIM + ch];
                    acc.x += h0.x + e0.x; acc.y += h0.y + e0.y;
                    acc.z += h0.z + e0.z; acc.w += h0.w + e0.w;
                }
            }
            ushort4 o; o.x = f2bf(acc.x); o.y = f2bf(acc.y); o.z = f2bf(acc.z); o.w = f2bf(acc.w);
            *(ushort4*)&As[(w * 8 + r8) * 264 + ch] = o;
        }
    }
    f32x4 acc2[4][2]{};
    __syncthreads();

    // ---- quarter-split GEMM ----
    #pragma unroll
    for (int q = 0; q < 4; ++q) {
        f32x4 acc1[4]{};
        const unsigned short* w1p = &Wt1[(size_t)(q * 128 + w * 16 + lrow) * DIM];
        #pragma unroll
        for (int kk = 0; kk < 8; ++kk) {
            const int kc = kk * 32 + lq * 8;
            bf16x8 b = *(const bf16x8*)&w1p[kc];
            bf16x8 a[4];
            #pragma unroll
            for (int mi = 0; mi < 4; ++mi)
                a[mi] = *(const bf16x8*)&As[(mi * 16 + lrow) * 264 + kc];
            #pragma unroll
            for (int mi = 0; mi < 4; ++mi)
                acc1[mi] = __builtin_amdgcn_mfma_f32_16x16x32_bf16(a[mi], b, acc1[mi], 0, 0, 0);
        }
        if (q > 0) __syncthreads();
        {
            int col = w * 16 + lrow;
            float bv = b1[q * 128 + col];
            #pragma unroll
            for (int mi = 0; mi < 4; ++mi)
                #pragma unroll
                for (int r = 0; r < 4; ++r)
                    Ts[(mi * 16 + lq * 4 + r) * 136 + col] = f2bf(fmaxf(acc1[mi][r] + bv, 0.f));
        }
        __syncthreads();
        #pragma unroll
        for (int kk = 0; kk < 4; ++kk) {
            const int kc = kk * 32 + lq * 8;
            bf16x8 a[4], b[2];
            #pragma unroll
            for (int mi = 0; mi < 4; ++mi)
                a[mi] = *(const bf16x8*)&Ts[(mi * 16 + lrow) * 136 + kc];
            #pragma unroll
            for (int ni = 0; ni < 2; ++ni)
                b[ni] = *(const bf16x8*)&Wt2[(size_t)(w * 32 + ni * 16 + lrow) * (2 * DIM) + q * 128 + kc];
            #pragma unroll
            for (int mi = 0; mi < 4; ++mi)
                #pragma unroll
                for (int ni = 0; ni < 2; ++ni)
                    acc2[mi][ni] = __builtin_amdgcn_mfma_f32_16x16x32_bf16(a[mi], b[ni], acc2[mi][ni], 0, 0, 0);
        }
    }

    // ---- epilogue: zdst store + stats atomics ----
    #pragma unroll
    for (int ni = 0; ni < 2; ++ni) {
        int col = w * 32 + ni * 16 + lrow;
        float bv = b2[col];
        float s = 0.f, q = 0.f;
        #pragma unroll
        for (int mi = 0; mi < 4; ++mi)
            #pragma unroll
            for (int r = 0; r < 4; ++r) {
                int row = rowBase + mi * 16 + lq * 4 + r;
                if (row < NNODES) {
                    float v = acc2[mi][ni][r] + bv;
                    zdst[(size_t)row * DIM + col] = f2bf(v);
                    s += v; q += v * v;
                }
            }
        s += __shfl_xor(s, 16); s += __shfl_xor(s, 32);
        q += __shfl_xor(q, 16); q += __shfl_xor(q, 32);
        if (lq == 0) {
            atomicAdd(&stats[col], s);
            atomicAdd(&stats[DIM + col], q);
        }
    }
}

// ---- pooled[g] = mean(relu(z*a+c)) over sorted segment; BN inline from stats ----
__global__ __launch_bounds__(256) void pool_seg(const unsigned short* __restrict__ z,
                                                const float* __restrict__ statsP,
                                                const float* __restrict__ g_,
                                                const float* __restrict__ b_,
                                                const int* __restrict__ start,
                                                float* __restrict__ pooled) {
    int g = blockIdx.x, ch = threadIdx.x;
    float mu = statsP[ch] / (float)NNODES;
    float var = statsP[256 + ch] / (float)NNODES - mu * mu;
    float a = g_[ch] * rsqrtf(var + 1e-5f);
    float c = b_[ch] - mu * a;
    int r0 = start[g], r1 = start[g + 1];
    float s = 0.f;
    for (int i = r0; i < r1; ++i)
        s += fmaxf(bf2f(z[(size_t)i * DIM + ch]) * a + c, 0.f);
    pooled[(size_t)g * DIM + ch] = s / fmaxf((float)(r1 - r0), 1.f);
}

// ---- head MLP ----
__global__ __launch_bounds__(128) void head_mlp(const float* __restrict__ pooled,
                                                const float* __restrict__ Wo1,
                                                const float* __restrict__ bo1,
                                                const float* __restrict__ Wo2,
                                                const float* __restrict__ bo2,
                                                float* __restrict__ out) {
    __shared__ float p[DIM];
    __shared__ float r0[128], r1[128];
    int g = blockIdx.x, j = threadIdx.x;
    for (int k = j; k < DIM; k += 128) p[k] = pooled[(size_t)g * DIM + k];
    __syncthreads();
    float acc = bo1[j];
    for (int k = 0; k < DIM; ++k) acc += p[k] * Wo1[k * 128 + j];
    float sp = (acc > 20.f) ? acc : log1pf(expf(acc));
    r0[j] = sp * Wo2[j * 2 + 0];
    r1[j] = sp * Wo2[j * 2 + 1];
    __syncthreads();
    for (int s = 64; s > 0; s >>= 1) {
        if (j < s) { r0[j] += r0[j + s]; r1[j] += r1[j + s]; }
        __syncthreads();
    }
    if (j == 0) {
        out[g * 2 + 0] = r0[0] + bo2[0];
        out[g * 2 + 1] = r1[0] + bo2[1];
    }
}

extern "C" void kernel_launch(void* const* d_in, const int* in_sizes, int n_in,
                              void* d_out, int out_size, void* d_ws, size_t ws_size,
                              hipStream_t stream) {
    (void)in_sizes; (void)n_in; (void)out_size;
    const int* x     = (const int*)d_in[0];
    const int* ei    = (const int*)d_in[1];
    const int* ea    = (const int*)d_in[2];
    const int* batch = (const int*)d_in[3];
    const float* xe1 = (const float*)d_in[4];
    const float* xe2 = (const float*)d_in[5];
    const float* ee1 = (const float*)d_in[6];
    const float* ee2 = (const float*)d_in[7];
    const float* W1  = (const float*)d_in[8];
    const float* b1  = (const float*)d_in[9];
    const float* W2  = (const float*)d_in[10];
    const float* b2  = (const float*)d_in[11];
    const float* bng = (const float*)d_in[12];
    const float* bnb = (const float*)d_in[13];
    const float* Wo1 = (const float*)d_in[14];
    const float* bo1 = (const float*)d_in[15];
    const float* Wo2 = (const float*)d_in[16];
    const float* bo2 = (const float*)d_in[17];
    float* out = (float*)d_out;

    if (ws_size < 112000000ull) return;   // need ~109 MB

    char* ws = (char*)d_ws;
    size_t off = 0;
    auto alloc = [&](size_t bytes) { void* p = ws + off; off += (bytes + 255) & ~255ull; return p; };
    unsigned short* zA  = (unsigned short*)alloc((size_t)NNODES * DIM * 2);
    unsigned short* zB  = (unsigned short*)alloc((size_t)NNODES * DIM * 2);
    unsigned short* Wt1 = (unsigned short*)alloc((size_t)NLAYERS * DIM * 2 * DIM * 2);
    unsigned short* Wt2 = (unsigned short*)alloc((size_t)NLAYERS * DIM * 2 * DIM * 2);
    float* etab         = (float*)alloc((size_t)NLAYERS * 15 * DIM * 4);
    float* stats        = (float*)alloc(3 * 512 * 4);          // 3-rotation [3][512]
    float* pooled       = (float*)alloc((size_t)NB * DIM * 4);
    int* gstart         = (int*)alloc((size_t)(NB + 1) * 4);
    int* rowptr         = (int*)alloc((size_t)(NNODES + 1) * 4);
    int* deg            = (int*)alloc((size_t)NNODES * 4);
    int* esrc           = (int*)alloc((size_t)NEDGES * 4);
    int* eattr          = (int*)alloc((size_t)NEDGES * 4);
    int* bsum           = (int*)alloc((size_t)NSB * 4);

    const int WTOT = DIM * 2 * DIM;  // 131072
    unsigned short* zb[2] = { zA, zB };

    transpose_w<<<dim3((WTOT + 255) / 256, NLAYERS), 256, 0, stream>>>(W1, Wt1, DIM, 2 * DIM);
    transpose_w<<<dim3((WTOT + 255) / 256, NLAYERS), 256, 0, stream>>>(W2, Wt2, 2 * DIM, DIM);
    build_etab<<<dim3(15, NLAYERS), DIM, 0, stream>>>(ee1, ee2, etab);
    zero_f32<<<2, 256, 0, stream>>>(stats, 512);   // layer 0's stats buffer

    zero_i32<<<(NNODES + 255) / 256, 256, 0, stream>>>(deg, NNODES);
    csr_hist<<<(NEDGES + 255) / 256, 256, 0, stream>>>(ei, deg);
    scan_blk<<<NSB, 1024, 0, stream>>>(deg, rowptr, bsum);
    scan_partials<<<1, 64, 0, stream>>>(bsum);
    scan_add<<<NSB, 1024, 0, stream>>>(rowptr, bsum);
    csr_fill<<<(NEDGES + 255) / 256, 256, 0, stream>>>(ei, ea, rowptr, deg, esrc, eattr);
    seg_starts<<<(NB + 1 + 255) / 256, 256, 0, stream>>>(batch, gstart);

    const int NBLK = (NNODES + 63) / 64;
    for (int l = 0; l < NLAYERS; ++l) {
        float* statsC = stats + (size_t)(l % 3) * 512;
        float* statsP = stats + (size_t)((l + 2) % 3) * 512;
        float* statsZ = stats + (size_t)((l + 1) % 3) * 512;
        if (l == 0)
            layer_k<0><<<NBLK, 512, 0, stream>>>(zb[0], zb[1], x, xe1, xe2, statsP, statsZ,
                                                 bng, bnb, etab, rowptr, esrc, eattr,
                                                 Wt1, b1, Wt2, b2, statsC);
        else
            layer_k<1><<<NBLK, 512, 0, stream>>>(zb[l & 1], zb[(l + 1) & 1], x, xe1, xe2, statsP, statsZ,
                                                 bng + (size_t)(l - 1) * DIM, bnb + (size_t)(l - 1) * DIM,
                                                 etab + (size_t)l * 15 * DIM, rowptr, esrc, eattr,
                                                 Wt1 + (size_t)l * WTOT, b1 + (size_t)l * 2 * DIM,
                                                 Wt2 + (size_t)l * WTOT, b2 + (size_t)l * DIM, statsC);
    }

    pool_seg<<<NB, DIM, 0, stream>>>(zb[NLAYERS & 1], stats + (size_t)((NLAYERS - 1) % 3) * 512,
                                     bng + (size_t)(NLAYERS - 1) * DIM, bnb + (size_t)(NLAYERS - 1) * DIM,
                                     gstart, pooled);
    head_mlp<<<NB, 128, 0, stream>>>(pooled, Wo1, bo1, Wo2, bo2, out);
}

// Round 17
// 1051.309 us; speedup vs baseline: 1.0727x; 1.0042x over previous
//
#include <hip/hip_runtime.h>

#define NNODES 100000
#define NEDGES 200000
#define NB     2048
#define DIM    256
#define NLAYERS 5
#define NSB    98   // ceil(100000/1024) scan blocks

typedef __bf16 bf16x8 __attribute__((ext_vector_type(8)));
typedef float  f32x4  __attribute__((ext_vector_type(4)));

__device__ __forceinline__ float bf2f(unsigned short u) {
    union { unsigned u; float f; } v; v.u = ((unsigned)u) << 16; return v.f;
}
__device__ __forceinline__ unsigned short f2bf(float f) {
    union { float f; unsigned u; } v; v.f = f;
    unsigned r = v.u + 0x7fff + ((v.u >> 16) & 1);   // RNE (finite values only)
    return (unsigned short)(r >> 16);
}
__device__ __forceinline__ float4 loadZ4(const unsigned short* z, size_t row, int ch) {
    ushort4 u = *(const ushort4*)&z[row * DIM + ch];
    float4 r; r.x = bf2f(u.x); r.y = bf2f(u.y); r.z = bf2f(u.z); r.w = bf2f(u.w); return r;
}

// zero deg[100000] and stats0[512] in one dispatch
__global__ void init_zero(int* __restrict__ deg, float* __restrict__ stats0) {
    int i = blockIdx.x * 256 + threadIdx.x;
    if (i < NNODES) deg[i] = 0;
    if (i < 512) stats0[i] = 0.f;
}

// ---- transpose+convert weights: W (L x K x Nw) fp32 -> Wt (L x Nw x K) bf16 ----
__global__ void transpose_w(const float* __restrict__ W,
                            unsigned short* __restrict__ Wt, int K, int Nw) {
    int l = blockIdx.y;
    int t = blockIdx.x * 256 + threadIdx.x;
    int total = K * Nw;
    if (t >= total) return;
    int k = t / Nw, n = t % Nw;
    Wt[(size_t)l * total + (size_t)n * K + k] = f2bf(W[(size_t)l * total + t]);
}

// ---- edge-embedding table ----
__global__ void build_etab(const float* __restrict__ ee1, const float* __restrict__ ee2,
                           float* __restrict__ etab) {
    int l = blockIdx.y, c = blockIdx.x, d = threadIdx.x;   // c in [0,15)
    etab[((size_t)l * 15 + c) * DIM + d] =
        ee1[((size_t)l * 5 + c / 3) * DIM + d] + ee2[((size_t)l * 3 + c % 3) * DIM + d];
}

// ---- CSR build ----
__global__ void csr_hist(const int* __restrict__ ei, int* __restrict__ deg) {
    int j = blockIdx.x * 256 + threadIdx.x;
    if (j < NEDGES) atomicAdd(&deg[ei[NEDGES + j]], 1);
}
__global__ __launch_bounds__(1024) void scan_blk(const int* __restrict__ deg,
                                                 int* __restrict__ rowptr,
                                                 int* __restrict__ bsum) {
    __shared__ int s[1024];
    int b = blockIdx.x, t = threadIdx.x, i = b * 1024 + t;
    s[t] = (i < NNODES) ? deg[i] : 0;
    __syncthreads();
    #pragma unroll
    for (int off = 1; off < 1024; off <<= 1) {
        int u = (t >= off) ? s[t - off] : 0;
        __syncthreads();
        s[t] += u;
        __syncthreads();
    }
    if (i < NNODES) rowptr[i + 1] = s[t];
    if (t == 1023) bsum[b] = s[1023];
}
__global__ void scan_partials(int* __restrict__ bsum) {
    if (threadIdx.x == 0) {
        int acc = 0;
        for (int k = 0; k < NSB; ++k) { acc += bsum[k]; bsum[k] = acc; }
    }
}
__global__ void scan_add(int* __restrict__ rowptr, const int* __restrict__ bsum) {
    int b = blockIdx.x, t = threadIdx.x, i = b * 1024 + t;
    if (b > 0 && i < NNODES) rowptr[i + 1] += bsum[b - 1];
    if (b == 0 && t == 0) rowptr[0] = 0;
}
__global__ void csr_fill(const int* __restrict__ ei, const int* __restrict__ ea,
                         const int* __restrict__ rowptr, int* __restrict__ deg,
                         int* __restrict__ esrc, int* __restrict__ eattr) {
    int j = blockIdx.x * 256 + threadIdx.x;
    if (j >= NEDGES) return;
    int d = ei[NEDGES + j];
    int pos = atomicSub(&deg[d], 1) - 1;
    int slot = rowptr[d] + pos;
    esrc[slot] = ei[j];
    eattr[slot] = ea[2 * j] * 3 + ea[2 * j + 1];
}

// ---- segment starts ----
__global__ void seg_starts(const int* __restrict__ batch, int* __restrict__ start) {
    int g = blockIdx.x * 256 + threadIdx.x;
    if (g > NB) return;
    int lo = 0, hi = NNODES;
    while (lo < hi) { int mid = (lo + hi) >> 1; if (batch[mid] < g) lo = mid + 1; else hi = mid; }
    start[g] = lo;
}

// ---- fused layer (r11 body, measured optimum): gather -> As -> quarter-split GEMM ----
// (512,6): 3 blocks/CU, JIT loads. MODE 0: h from embeddings; MODE 1: BN inline.
template <int MODE>
__global__ __launch_bounds__(512, 6) void layer_k(const unsigned short* __restrict__ zsrc,
                                                  unsigned short* __restrict__ zdst,
                                                  const int* __restrict__ x,
                                                  const float* __restrict__ xe1,
                                                  const float* __restrict__ xe2,
                                                  const float* __restrict__ statsP,
                                                  float* __restrict__ statsZ,
                                                  const float* __restrict__ g_,
                                                  const float* __restrict__ b_,
                                                  const float* __restrict__ etab_l,
                                                  const int* __restrict__ rowptr,
                                                  const int* __restrict__ esrc,
                                                  const int* __restrict__ eattr,
                                                  const unsigned short* __restrict__ Wt1,
                                                  const float* __restrict__ b1,
                                                  const unsigned short* __restrict__ Wt2,
                                                  const float* __restrict__ b2,
                                                  float* __restrict__ stats) {
    __shared__ unsigned short As[64 * 264];   // 33792 B
    __shared__ unsigned short Ts[64 * 136];   // 17408 B (one t-quarter)

    const int rowBase = blockIdx.x * 64;
    const int tid = threadIdx.x;
    const int lane = tid & 63, w = tid >> 6;
    const int lrow = lane & 15, lq = lane >> 4;

    if (blockIdx.x == 0) statsZ[tid] = 0.f;

    // ---- stage A: fused gather into As ----
    {
        const int ch = lane * 4;
        float4 a4, c4;
        if (MODE == 1) {
            float4 s4 = *(const float4*)&statsP[ch];
            float4 q4 = *(const float4*)&statsP[256 + ch];
            float4 g4 = *(const float4*)&g_[ch];
            float4 b4 = *(const float4*)&b_[ch];
            const float invN = 1.0f / (float)NNODES;
            float mux = s4.x * invN, muy = s4.y * invN, muz = s4.z * invN, muw = s4.w * invN;
            a4.x = g4.x * rsqrtf(q4.x * invN - mux * mux + 1e-5f);
            a4.y = g4.y * rsqrtf(q4.y * invN - muy * muy + 1e-5f);
            a4.z = g4.z * rsqrtf(q4.z * invN - muz * muz + 1e-5f);
            a4.w = g4.w * rsqrtf(q4.w * invN - muw * muw + 1e-5f);
            c4.x = b4.x - mux * a4.x; c4.y = b4.y - muy * a4.y;
            c4.z = b4.z - muz * a4.z; c4.w = b4.w - muw * a4.w;
        }
        auto hrow = [&](int row) -> float4 {
            if (MODE == 0) {
                int i0 = x[2 * row], i1 = x[2 * row + 1];
                float4 u = *(const float4*)&xe1[(size_t)i0 * DIM + ch];
                float4 v = *(const float4*)&xe2[(size_t)i1 * DIM + ch];
                return make_float4(u.x + v.x, u.y + v.y, u.z + v.z, u.w + v.w);
            } else {
                float4 h = loadZ4(zsrc, (size_t)row, ch);
                h.x = fmaxf(h.x * a4.x + c4.x, 0.f); h.y = fmaxf(h.y * a4.y + c4.y, 0.f);
                h.z = fmaxf(h.z * a4.z + c4.z, 0.f); h.w = fmaxf(h.w * a4.w + c4.w, 0.f);
                return h;
            }
        };
        float4 se = *(const float4*)&etab_l[12 * DIM + ch];   // self edge (bt=4,bd=0)
        #pragma unroll
        for (int r8 = 0; r8 < 8; ++r8) {
            int row = rowBase + w * 8 + r8;
            float4 acc = make_float4(0.f, 0.f, 0.f, 0.f);
            if (row < NNODES) {
                float4 hv = hrow(row);
                acc = make_float4(hv.x + se.x, hv.y + se.y, hv.z + se.z, hv.w + se.w);
                int r0 = rowptr[row], r1 = rowptr[row + 1];
                int e = r0;
                for (; e + 2 <= r1; e += 2) {
                    int s0 = esrc[e], c0 = eattr[e];
                    int s1 = esrc[e + 1], c1 = eattr[e + 1];
                    float4 h0 = hrow(s0);
                    float4 h1 = hrow(s1);
                    float4 e0 = *(const float4*)&etab_l[c0 * DIM + ch];
                    float4 e1 = *(const float4*)&etab_l[c1 * DIM + ch];
                    acc.x += h0.x + e0.x + h1.x + e1.x; acc.y += h0.y + e0.y + h1.y + e1.y;
                    acc.z += h0.z + e0.z + h1.z + e1.z; acc.w += h0.w + e0.w + h1.w + e1.w;
                }
                if (e < r1) {
                    int s0 = esrc[e], c0 = eattr[e];
                    float4 h0 = hrow(s0);
                    float4 e0 = *(const float4*)&etab_l[c0 * DIM + ch];
                    acc.x += h0.x + e0.x; acc.y += h0.y + e0.y;
                    acc.z += h0.z + e0.z; acc.w += h0.w + e0.w;
                }
            }
            ushort4 o; o.x = f2bf(acc.x); o.y = f2bf(acc.y); o.z = f2bf(acc.z); o.w = f2bf(acc.w);
            *(ushort4*)&As[(w * 8 + r8) * 264 + ch] = o;
        }
    }
    f32x4 acc2[4][2]{};
    __syncthreads();

    // ---- quarter-split GEMM ----
    #pragma unroll
    for (int q = 0; q < 4; ++q) {
        f32x4 acc1[4]{};
        const unsigned short* w1p = &Wt1[(size_t)(q * 128 + w * 16 + lrow) * DIM];
        #pragma unroll
        for (int kk = 0; kk < 8; ++kk) {
            const int kc = kk * 32 + lq * 8;
            bf16x8 b = *(const bf16x8*)&w1p[kc];
            bf16x8 a[4];
            #pragma unroll
            for (int mi = 0; mi < 4; ++mi)
                a[mi] = *(const bf16x8*)&As[(mi * 16 + lrow) * 264 + kc];
            #pragma unroll
            for (int mi = 0; mi < 4; ++mi)
                acc1[mi] = __builtin_amdgcn_mfma_f32_16x16x32_bf16(a[mi], b, acc1[mi], 0, 0, 0);
        }
        if (q > 0) __syncthreads();
        {
            int col = w * 16 + lrow;
            float bv = b1[q * 128 + col];
            #pragma unroll
            for (int mi = 0; mi < 4; ++mi)
                #pragma unroll
                for (int r = 0; r < 4; ++r)
                    Ts[(mi * 16 + lq * 4 + r) * 136 + col] = f2bf(fmaxf(acc1[mi][r] + bv, 0.f));
        }
        __syncthreads();
        #pragma unroll
        for (int kk = 0; kk < 4; ++kk) {
            const int kc = kk * 32 + lq * 8;
            bf16x8 a[4], b[2];
            #pragma unroll
            for (int mi = 0; mi < 4; ++mi)
                a[mi] = *(const bf16x8*)&Ts[(mi * 16 + lrow) * 136 + kc];
            #pragma unroll
            for (int ni = 0; ni < 2; ++ni)
                b[ni] = *(const bf16x8*)&Wt2[(size_t)(w * 32 + ni * 16 + lrow) * (2 * DIM) + q * 128 + kc];
            #pragma unroll
            for (int mi = 0; mi < 4; ++mi)
                #pragma unroll
                for (int ni = 0; ni < 2; ++ni)
                    acc2[mi][ni] = __builtin_amdgcn_mfma_f32_16x16x32_bf16(a[mi], b[ni], acc2[mi][ni], 0, 0, 0);
        }
    }

    // ---- epilogue: zdst store + stats atomics ----
    #pragma unroll
    for (int ni = 0; ni < 2; ++ni) {
        int col = w * 32 + ni * 16 + lrow;
        float bv = b2[col];
        float s = 0.f, q = 0.f;
        #pragma unroll
        for (int mi = 0; mi < 4; ++mi)
            #pragma unroll
            for (int r = 0; r < 4; ++r) {
                int row = rowBase + mi * 16 + lq * 4 + r;
                if (row < NNODES) {
                    float v = acc2[mi][ni][r] + bv;
                    zdst[(size_t)row * DIM + col] = f2bf(v);
                    s += v; q += v * v;
                }
            }
        s += __shfl_xor(s, 16); s += __shfl_xor(s, 32);
        q += __shfl_xor(q, 16); q += __shfl_xor(q, 32);
        if (lq == 0) {
            atomicAdd(&stats[col], s);
            atomicAdd(&stats[DIM + col], q);
        }
    }
}

// ---- fused pool + head: block g pools its segment (BN inline) then runs the head MLP ----
__global__ __launch_bounds__(256) void pool_head(const unsigned short* __restrict__ z,
                                                 const float* __restrict__ statsP,
                                                 const float* __restrict__ g_,
                                                 const float* __restrict__ b_,
                                                 const int* __restrict__ start,
                                                 const float* __restrict__ Wo1,
                                                 const float* __restrict__ bo1,
                                                 const float* __restrict__ Wo2,
                                                 const float* __restrict__ bo2,
                                                 float* __restrict__ out) {
    __shared__ float p[DIM];
    __shared__ float r0[128], r1[128];
    int g = blockIdx.x, j = threadIdx.x;

    // phase 1: pooled row (one channel per thread)
    {
        int ch = j;
        float mu = statsP[ch] / (float)NNODES;
        float var = statsP[256 + ch] / (float)NNODES - mu * mu;
        float a = g_[ch] * rsqrtf(var + 1e-5f);
        float c = b_[ch] - mu * a;
        int rr0 = start[g], rr1 = start[g + 1];
        float s = 0.f;
        for (int i = rr0; i < rr1; ++i)
            s += fmaxf(bf2f(z[(size_t)i * DIM + ch]) * a + c, 0.f);
        p[ch] = s / fmaxf((float)(rr1 - rr0), 1.f);
    }
    __syncthreads();

    // phase 2: head MLP (first 128 threads)
    if (j < 128) {
        float acc = bo1[j];
        for (int k = 0; k < DIM; ++k) acc += p[k] * Wo1[k * 128 + j];
        float sp = (acc > 20.f) ? acc : log1pf(expf(acc));
        r0[j] = sp * Wo2[j * 2 + 0];
        r1[j] = sp * Wo2[j * 2 + 1];
    }
    __syncthreads();
    for (int s = 64; s > 0; s >>= 1) {
        if (j < s) { r0[j] += r0[j + s]; r1[j] += r1[j + s]; }
        __syncthreads();
    }
    if (j == 0) {
        out[g * 2 + 0] = r0[0] + bo2[0];
        out[g * 2 + 1] = r1[0] + bo2[1];
    }
}

extern "C" void kernel_launch(void* const* d_in, const int* in_sizes, int n_in,
                              void* d_out, int out_size, void* d_ws, size_t ws_size,
                              hipStream_t stream) {
    (void)in_sizes; (void)n_in; (void)out_size;
    const int* x     = (const int*)d_in[0];
    const int* ei    = (const int*)d_in[1];
    const int* ea    = (const int*)d_in[2];
    const int* batch = (const int*)d_in[3];
    const float* xe1 = (const float*)d_in[4];
    const float* xe2 = (const float*)d_in[5];
    const float* ee1 = (const float*)d_in[6];
    const float* ee2 = (const float*)d_in[7];
    const float* W1  = (const float*)d_in[8];
    const float* b1  = (const float*)d_in[9];
    const float* W2  = (const float*)d_in[10];
    const float* b2  = (const float*)d_in[11];
    const float* bng = (const float*)d_in[12];
    const float* bnb = (const float*)d_in[13];
    const float* Wo1 = (const float*)d_in[14];
    const float* bo1 = (const float*)d_in[15];
    const float* Wo2 = (const float*)d_in[16];
    const float* bo2 = (const float*)d_in[17];
    float* out = (float*)d_out;

    if (ws_size < 112000000ull) return;   // need ~109 MB

    char* ws = (char*)d_ws;
    size_t off = 0;
    auto alloc = [&](size_t bytes) { void* p = ws + off; off += (bytes + 255) & ~255ull; return p; };
    unsigned short* zA  = (unsigned short*)alloc((size_t)NNODES * DIM * 2);
    unsigned short* zB  = (unsigned short*)alloc((size_t)NNODES * DIM * 2);
    unsigned short* Wt1 = (unsigned short*)alloc((size_t)NLAYERS * DIM * 2 * DIM * 2);
    unsigned short* Wt2 = (unsigned short*)alloc((size_t)NLAYERS * DIM * 2 * DIM * 2);
    float* etab         = (float*)alloc((size_t)NLAYERS * 15 * DIM * 4);
    float* stats        = (float*)alloc(3 * 512 * 4);          // 3-rotation [3][512]
    int* gstart         = (int*)alloc((size_t)(NB + 1) * 4);
    int* rowptr         = (int*)alloc((size_t)(NNODES + 1) * 4);
    int* deg            = (int*)alloc((size_t)NNODES * 4);
    int* esrc           = (int*)alloc((size_t)NEDGES * 4);
    int* eattr          = (int*)alloc((size_t)NEDGES * 4);
    int* bsum           = (int*)alloc((size_t)NSB * 4);

    const int WTOT = DIM * 2 * DIM;  // 131072
    unsigned short* zb[2] = { zA, zB };

    transpose_w<<<dim3((WTOT + 255) / 256, NLAYERS), 256, 0, stream>>>(W1, Wt1, DIM, 2 * DIM);
    transpose_w<<<dim3((WTOT + 255) / 256, NLAYERS), 256, 0, stream>>>(W2, Wt2, 2 * DIM, DIM);
    build_etab<<<dim3(15, NLAYERS), DIM, 0, stream>>>(ee1, ee2, etab);

    init_zero<<<(NNODES + 255) / 256, 256, 0, stream>>>(deg, stats);
    csr_hist<<<(NEDGES + 255) / 256, 256, 0, stream>>>(ei, deg);
    scan_blk<<<NSB, 1024, 0, stream>>>(deg, rowptr, bsum);
    scan_partials<<<1, 64, 0, stream>>>(bsum);
    scan_add<<<NSB, 1024, 0, stream>>>(rowptr, bsum);
    csr_fill<<<(NEDGES + 255) / 256, 256, 0, stream>>>(ei, ea, rowptr, deg, esrc, eattr);
    seg_starts<<<(NB + 1 + 255) / 256, 256, 0, stream>>>(batch, gstart);

    const int NBLK = (NNODES + 63) / 64;
    for (int l = 0; l < NLAYERS; ++l) {
        float* statsC = stats + (size_t)(l % 3) * 512;
        float* statsP = stats + (size_t)((l + 2) % 3) * 512;
        float* statsZ = stats + (size_t)((l + 1) % 3) * 512;
        if (l == 0)
            layer_k<0><<<NBLK, 512, 0, stream>>>(zb[0], zb[1], x, xe1, xe2, statsP, statsZ,
                                                 bng, bnb, etab, rowptr, esrc, eattr,
                                                 Wt1, b1, Wt2, b2, statsC);
        else
            layer_k<1><<<NBLK, 512, 0, stream>>>(zb[l & 1], zb[(l + 1) & 1], x, xe1, xe2, statsP, statsZ,
                                                 bng + (size_t)(l - 1) * DIM, bnb + (size_t)(l - 1) * DIM,
                                                 etab + (size_t)l * 15 * DIM, rowptr, esrc, eattr,
                                                 Wt1 + (size_t)l * WTOT, b1 + (size_t)l * 2 * DIM,
                                                 Wt2 + (size_t)l * WTOT, b2 + (size_t)l * DIM, statsC);
    }

    pool_head<<<NB, 256, 0, stream>>>(zb[NLAYERS & 1], stats + (size_t)((NLAYERS - 1) % 3) * 512,
                                      bng + (size_t)(NLAYERS - 1) * DIM, bnb + (size_t)(NLAYERS - 1) * DIM,
                                      gstart, Wo1, bo1, Wo2, bo2, out);
}